// Round 1
// baseline (745.434 us; speedup 1.0000x reference)
//
#include <hip/hip_runtime.h>
#include <stdint.h>

typedef __bf16 bf16_t;
typedef bf16_t bf16x8 __attribute__((ext_vector_type(8)));
typedef float f32x4 __attribute__((ext_vector_type(4)));
typedef unsigned short u16x8 __attribute__((ext_vector_type(8)));

#define KDIM 512

__device__ __forceinline__ unsigned short f2bf(float f) {
  unsigned int u = __float_as_uint(f);
  u = (u + 0x7FFFu + ((u >> 16) & 1u)) >> 16;
  return (unsigned short)u;
}

// ---------------- fp32 -> bf16 conversion (vectorized, 8 elems/thread) ----------------
__global__ void cvt_kernel(const float* __restrict__ src, unsigned short* __restrict__ dst, int n8) {
  int i = blockIdx.x * blockDim.x + threadIdx.x;
  if (i >= n8) return;
  const float4* s = (const float4*)src;
  float4 a = s[2 * (size_t)i], b = s[2 * (size_t)i + 1];
  u16x8 r;
  r[0] = f2bf(a.x); r[1] = f2bf(a.y); r[2] = f2bf(a.z); r[3] = f2bf(a.w);
  r[4] = f2bf(b.x); r[5] = f2bf(b.y); r[6] = f2bf(b.z); r[7] = f2bf(b.w);
  *(u16x8*)(dst + (size_t)8 * i) = r;
}

// ---------------- async global->LDS staging of a 128x64 bf16 tile ----------------
// LDS layout: row-major [128][64] bf16 (128 B/row), XOR-swizzled: LDS slot (row, colb)
// holds the global element at byte-col (colb ^ ((row&7)<<4)).  Dest is linear
// (wave-uniform base + lane*16), source is inverse-swizzled (rule #21).
__device__ __forceinline__ void gload_lds16(const unsigned short* g, unsigned short* l) {
  __builtin_amdgcn_global_load_lds(
      (const __attribute__((address_space(1))) void*)g,
      (__attribute__((address_space(3))) void*)l, 16, 0, 0);
}

__device__ __forceinline__ void stage_tile(const unsigned short* __restrict__ gbase, // @ [row0][k0]
                                           unsigned short* lds, int tid) {
#pragma unroll
  for (int i = 0; i < 4; ++i) {
    int lin = i * 4096 + tid * 16;        // linear byte offset in LDS
    int row = lin >> 7;                   // 128 B per row
    int colb = lin & 127;
    int scolb = colb ^ ((row & 7) << 4);  // inverse-swizzled source byte col
    gload_lds16(gbase + (size_t)row * KDIM + (scolb >> 1), lds + (lin >> 1));
  }
}

// ---------------- shared 128x128 bf16 MFMA tile compute ----------------
// 4 waves (2x2), each wave owns a 64x64 sub-tile = 4x4 fragments of 16x16.
__device__ __forceinline__ void gemm_tile_k512(
    const unsigned short* __restrict__ Ag, const unsigned short* __restrict__ Bg,
    unsigned short* ldsA, unsigned short* ldsB, int tid, f32x4 acc[4][4]) {
  int lane = tid & 63;
  int w = tid >> 6;
  int wr0 = (w >> 1) * 64, wc0 = (w & 1) * 64;
  for (int kt = 0; kt < KDIM / 64; ++kt) {
    __syncthreads();
    stage_tile(Ag + kt * 64, ldsA, tid);
    stage_tile(Bg + kt * 64, ldsB, tid);
    __syncthreads();
#pragma unroll
    for (int kk = 0; kk < 2; ++kk) {
      bf16x8 av[4], bv[4];
      int cb = kk * 64 + (lane >> 4) * 16;  // byte col of this lane's 8 k-elems
#pragma unroll
      for (int f = 0; f < 4; ++f) {
        int ra = wr0 + f * 16 + (lane & 15);
        av[f] = *(const bf16x8*)((const char*)ldsA + ra * 128 + (cb ^ ((ra & 7) << 4)));
        int rb = wc0 + f * 16 + (lane & 15);
        bv[f] = *(const bf16x8*)((const char*)ldsB + rb * 128 + (cb ^ ((rb & 7) << 4)));
      }
#pragma unroll
      for (int fi = 0; fi < 4; ++fi)
#pragma unroll
        for (int fj = 0; fj < 4; ++fj)
          acc[fi][fj] = __builtin_amdgcn_mfma_f32_16x16x32_bf16(av[fi], bv[fj], acc[fi][fj], 0, 0, 0);
    }
  }
}

// ---------------- expert GEMM: h = x @ W^T, remap-write into stitched (bf16) ----------------
// A: [M=128*L, 512] bf16; B(W): [p*512, 512] bf16; C elem (m, n_col) -> stitched row
// (ebase + m/L)*336 + (m%L)*p + (n_col>>9), col (n_col&511).
__global__ __launch_bounds__(256) void expert_gemm(
    const unsigned short* __restrict__ A, const unsigned short* __restrict__ B,
    const float* __restrict__ bias, unsigned short* __restrict__ stitched,
    int L, int p, int ebase) {
  __shared__ unsigned short ldsA[128 * 64];
  __shared__ unsigned short ldsB[128 * 64];
  int tid = threadIdx.x;
  int lane = tid & 63, w = tid >> 6;
  int wr0 = (w >> 1) * 64, wc0 = (w & 1) * 64;
  int tileM = blockIdx.x, tileN = blockIdx.y;
  const unsigned short* Ag = A + (size_t)tileM * 128 * KDIM;
  const unsigned short* Bg = B + (size_t)tileN * 128 * KDIM;
  f32x4 acc[4][4] = {};
  gemm_tile_k512(Ag, Bg, ldsA, ldsB, tid, acc);

  int jblk = (tileN * 128) >> 9;
  int d2base = (tileN * 128) & 511;
#pragma unroll
  for (int fi = 0; fi < 4; ++fi) {
#pragma unroll
    for (int fj = 0; fj < 4; ++fj) {
      int d2 = d2base + wc0 + fj * 16 + (lane & 15);
      float bv = bias[jblk * 512 + d2];
#pragma unroll
      for (int r = 0; r < 4; ++r) {
        int m = tileM * 128 + wr0 + fi * 16 + (lane >> 4) * 4 + r;
        int n = m / L, li = m % L;
        size_t srow = (size_t)(ebase + n) * 336 + (size_t)li * p + jblk;
        stitched[srow * 512 + d2] = f2bf(acc[fi][fj][r] + bv);
      }
    }
  }
}

// ---------------- projection GEMM + gate-scale + scatter-add ----------------
// A: stitched [172032, 512] bf16; B: Wp [512,512] bf16. Row m -> nnz n=m/336, t=m%336;
// out[batch_index[n]][t][col] += gate * (acc + bp[col]).  Exactly 2 adds/elem (atomic, commutative).
__global__ __launch_bounds__(256) void proj_gemm(
    const unsigned short* __restrict__ A, const unsigned short* __restrict__ B,
    const float* __restrict__ bp, const float* __restrict__ gates,
    const int* __restrict__ bidx, const int* __restrict__ eidx,
    float* __restrict__ out) {
  __shared__ unsigned short ldsA[128 * 64];
  __shared__ unsigned short ldsB[128 * 64];
  int tid = threadIdx.x;
  int lane = tid & 63, w = tid >> 6;
  int wr0 = (w >> 1) * 64, wc0 = (w & 1) * 64;
  int tileM = blockIdx.x, tileN = blockIdx.y;
  const unsigned short* Ag = A + (size_t)tileM * 128 * KDIM;
  const unsigned short* Bg = B + (size_t)tileN * 128 * KDIM;
  f32x4 acc[4][4] = {};
  gemm_tile_k512(Ag, Bg, ldsA, ldsB, tid, acc);

#pragma unroll
  for (int fi = 0; fi < 4; ++fi) {
#pragma unroll
    for (int fj = 0; fj < 4; ++fj) {
      int col = tileN * 128 + wc0 + fj * 16 + (lane & 15);
      float bv = bp[col];
#pragma unroll
      for (int r = 0; r < 4; ++r) {
        int m = tileM * 128 + wr0 + fi * 16 + (lane >> 4) * 4 + r;
        int nn = m / 336, t = m - nn * 336;
        int b = bidx[nn];
        float g = gates[b * 4 + eidx[nn]];
        atomicAdd(out + ((size_t)b * 336 + t) * 512 + col, (acc[fi][fj][r] + bv) * g);
      }
    }
  }
}

extern "C" void kernel_launch(void* const* d_in, const int* in_sizes, int n_in,
                              void* d_out, int out_size, void* d_ws, size_t ws_size,
                              hipStream_t stream) {
  const float* xs[4]   = {(const float*)d_in[0], (const float*)d_in[3], (const float*)d_in[6], (const float*)d_in[9]};
  const float* Wf[4]   = {(const float*)d_in[1], (const float*)d_in[4], (const float*)d_in[7], (const float*)d_in[10]};
  const float* bias[4] = {(const float*)d_in[2], (const float*)d_in[5], (const float*)d_in[8], (const float*)d_in[11]};
  const float* gates = (const float*)d_in[12];
  const float* Wp    = (const float*)d_in[13];
  const float* bp    = (const float*)d_in[14];
  const int* bidx    = (const int*)d_in[15];
  const int* eidx    = (const int*)d_in[16];

  static const int xs_elems[4] = {5505024, 2752512, 1835008, 917504};
  static const int W_elems[4]  = {1048576, 2097152, 3145728, 6291456};
  static const int Ls[4] = {84, 42, 28, 14};
  static const int Ps[4] = {4, 8, 12, 24};

  unsigned short* w = (unsigned short*)d_ws;
  unsigned short* xsb[4]; unsigned short* Wb[4];
  size_t off = 0;
  for (int i = 0; i < 4; i++) { xsb[i] = w + off; off += xs_elems[i]; }
  for (int i = 0; i < 4; i++) { Wb[i]  = w + off; off += W_elems[i]; }
  unsigned short* Wpb = w + off; off += 262144;
  unsigned short* stitched = w + off; off += (size_t)512 * 336 * 512;

  // fp32 -> bf16 conversions
  for (int i = 0; i < 4; i++) {
    int n8 = xs_elems[i] / 8;
    cvt_kernel<<<(n8 + 255) / 256, 256, 0, stream>>>(xs[i], xsb[i], n8);
    n8 = W_elems[i] / 8;
    cvt_kernel<<<(n8 + 255) / 256, 256, 0, stream>>>(Wf[i], Wb[i], n8);
  }
  cvt_kernel<<<(262144 / 8 + 255) / 256, 256, 0, stream>>>(Wp, Wpb, 262144 / 8);

  // zero output (atomically accumulated below; harness does not re-poison between replays)
  hipMemsetAsync(d_out, 0, (size_t)out_size * sizeof(float), stream);

  // expert GEMMs: grid (M/128, N/128) = (L_i, 4*p_i) -> 1344 blocks each
  for (int i = 0; i < 4; i++) {
    dim3 grid(Ls[i], 4 * Ps[i]);
    expert_gemm<<<grid, 256, 0, stream>>>(xsb[i], Wb[i], bias[i], stitched, Ls[i], Ps[i], i * 128);
  }

  // projection GEMM + gated scatter-add: M=512*336=172032 -> 1344 x 4 tiles
  proj_gemm<<<dim3(1344, 4), 256, 0, stream>>>(stitched, Wpb, bp, gates, bidx, eidx, (float*)d_out);
}

// Round 2
// 474.824 us; speedup vs baseline: 1.5699x; 1.5699x over previous
//
#include <hip/hip_runtime.h>
#include <stdint.h>

typedef __bf16 bf16_t;
typedef bf16_t bf16x8 __attribute__((ext_vector_type(8)));
typedef float f32x4 __attribute__((ext_vector_type(4)));
typedef unsigned short u16x8 __attribute__((ext_vector_type(8)));

#define KDIM 512

__device__ __forceinline__ unsigned short f2bf(float f) {
  unsigned int u = __float_as_uint(f);
  u = (u + 0x7FFFu + ((u >> 16) & 1u)) >> 16;
  return (unsigned short)u;
}

// ---------------- fp32 -> bf16 conversion (vectorized, 8 elems/thread) ----------------
__global__ void cvt_kernel(const float* __restrict__ src, unsigned short* __restrict__ dst, int n8) {
  int i = blockIdx.x * blockDim.x + threadIdx.x;
  if (i >= n8) return;
  const float4* s = (const float4*)src;
  float4 a = s[2 * (size_t)i], b = s[2 * (size_t)i + 1];
  u16x8 r;
  r[0] = f2bf(a.x); r[1] = f2bf(a.y); r[2] = f2bf(a.z); r[3] = f2bf(a.w);
  r[4] = f2bf(b.x); r[5] = f2bf(b.y); r[6] = f2bf(b.z); r[7] = f2bf(b.w);
  *(u16x8*)(dst + (size_t)8 * i) = r;
}

// ---------------- transpose + cvt: W [p*512, 512] fp32 -> WtB [p][512 d][512 e] bf16 ----------------
// WtB[j][d][e] = W[j*512+e, d].  64x64 LDS tile, conflict-free (stride 65).
__global__ __launch_bounds__(256) void transpose_cvt(const float* __restrict__ W,
                                                     unsigned short* __restrict__ Wt) {
  __shared__ float tile[64][65];
  int q0 = blockIdx.x * 64;  // source row block (q = j*512+e)
  int d0 = blockIdx.y * 64;  // source col block (d)
  int t = threadIdx.x;
  int c = t & 63, r4 = t >> 6;
#pragma unroll
  for (int i = 0; i < 16; ++i) {
    int row = r4 + i * 4;
    tile[row][c] = W[(size_t)(q0 + row) * 512 + d0 + c];
  }
  __syncthreads();
  int j = q0 >> 9, e0 = q0 & 511;
  size_t obase = (size_t)j * 262144 + (size_t)d0 * 512 + e0;
#pragma unroll
  for (int i = 0; i < 16; ++i) {
    int dd = r4 + i * 4;
    Wt[obase + (size_t)dd * 512 + c] = f2bf(tile[c][dd]);
  }
}

// ---------------- fused bias: bf[j*512+o] = sum_e Wp[o,e]*b[j*512+e] + bp[o] ----------------
__global__ void bias_fuse(const float* __restrict__ Wp, const float* __restrict__ b,
                          const float* __restrict__ bp, float* __restrict__ bf) {
  int j = blockIdx.x;
  for (int o = threadIdx.x; o < 512; o += blockDim.x) {
    float s = bp[o];
    const float* wr = Wp + (size_t)o * 512;
    const float* br = b + (size_t)j * 512;
    for (int e = 0; e < 512; ++e) s += wr[e] * br[e];
    bf[(size_t)j * 512 + o] = s;
  }
}

// ---------------- async global->LDS staging of a 128x64 bf16 tile (rule #21 swizzle) ----------------
__device__ __forceinline__ void gload_lds16(const unsigned short* g, unsigned short* l) {
  __builtin_amdgcn_global_load_lds(
      (const __attribute__((address_space(1))) void*)g,
      (__attribute__((address_space(3))) void*)l, 16, 0, 0);
}

__device__ __forceinline__ void stage_tile(const unsigned short* __restrict__ gbase,
                                           unsigned short* lds, int tid) {
#pragma unroll
  for (int i = 0; i < 4; ++i) {
    int lin = i * 4096 + tid * 16;        // linear byte offset in LDS
    int row = lin >> 7;                   // 128 B per row
    int colb = lin & 127;
    int scolb = colb ^ ((row & 7) << 4);  // inverse-swizzled source byte col
    gload_lds16(gbase + (size_t)row * KDIM + (scolb >> 1), lds + (lin >> 1));
  }
}

// ---------------- shared 128x128 bf16 MFMA tile compute (4 waves, 2x2) ----------------
__device__ __forceinline__ void gemm_tile_k512(
    const unsigned short* __restrict__ Ag, const unsigned short* __restrict__ Bg,
    unsigned short* ldsA, unsigned short* ldsB, int tid, f32x4 acc[4][4]) {
  int lane = tid & 63;
  int w = tid >> 6;
  int wr0 = (w >> 1) * 64, wc0 = (w & 1) * 64;
  for (int kt = 0; kt < KDIM / 64; ++kt) {
    __syncthreads();
    stage_tile(Ag + kt * 64, ldsA, tid);
    stage_tile(Bg + kt * 64, ldsB, tid);
    __syncthreads();
#pragma unroll
    for (int kk = 0; kk < 2; ++kk) {
      bf16x8 av[4], bv[4];
      int cb = kk * 64 + (lane >> 4) * 16;
#pragma unroll
      for (int f = 0; f < 4; ++f) {
        int ra = wr0 + f * 16 + (lane & 15);
        av[f] = *(const bf16x8*)((const char*)ldsA + ra * 128 + (cb ^ ((ra & 7) << 4)));
        int rb = wc0 + f * 16 + (lane & 15);
        bv[f] = *(const bf16x8*)((const char*)ldsB + rb * 128 + (cb ^ ((rb & 7) << 4)));
      }
#pragma unroll
      for (int fi = 0; fi < 4; ++fi)
#pragma unroll
        for (int fj = 0; fj < 4; ++fj)
          acc[fi][fj] = __builtin_amdgcn_mfma_f32_16x16x32_bf16(av[fi], bv[fj], acc[fi][fj], 0, 0, 0);
    }
  }
}

// ---------------- weight-fuse GEMM: Wf[(j,o), d] = sum_e Wp[o,e] * WtB[j][d][e] ----------------
__global__ __launch_bounds__(256) void fuse_gemm(
    const unsigned short* __restrict__ Wpb,  // [512 o, 512 e] bf16
    const unsigned short* __restrict__ WtB,  // [p][512 d][512 e] bf16
    unsigned short* __restrict__ Wf) {       // [p*512, 512] bf16
  __shared__ unsigned short ldsA[128 * 64];
  __shared__ unsigned short ldsB[128 * 64];
  int tid = threadIdx.x;
  int lane = tid & 63, w = tid >> 6;
  int wr0 = (w >> 1) * 64, wc0 = (w & 1) * 64;
  int tileM = blockIdx.x, tileN = blockIdx.y;
  int j = (tileM * 128) >> 9;
  const unsigned short* Ag = Wpb + (size_t)((tileM * 128) & 511) * 512;
  const unsigned short* Bg = WtB + (size_t)j * 262144 + (size_t)(tileN * 128) * 512;
  f32x4 acc[4][4] = {};
  gemm_tile_k512(Ag, Bg, ldsA, ldsB, tid, acc);
#pragma unroll
  for (int fi = 0; fi < 4; ++fi)
#pragma unroll
    for (int fj = 0; fj < 4; ++fj) {
      int col = tileN * 128 + wc0 + fj * 16 + (lane & 15);
#pragma unroll
      for (int r = 0; r < 4; ++r) {
        int m = tileM * 128 + wr0 + fi * 16 + (lane >> 4) * 4 + r;
        Wf[(size_t)m * 512 + col] = f2bf(acc[fi][fj][r]);
      }
    }
}

// ---------------- fused expert GEMM + gate + scatter-combine ----------------
// C[m, q'] = x[m,:] @ Wf[q',:];  m -> (n = m/L, li = m%L);  q' -> (j = q'>>9, o = q'&511)
// out[b, li*P+j, o] (store|add) g * (C + bf[q']),  b = bidx[ebase+n], g = gates[b,eidx].
// First-writer per batch is static: b%4==3 -> expert 0, else expert b%4.  Plain RMW is
// race-free: one touch per element per kernel; the 4 expert kernels are stream-serialized.
template <int L, int P, int EXPERT>
__global__ __launch_bounds__(256) void expert_fused(
    const unsigned short* __restrict__ A,   // x bf16 [128*L, 512]
    const unsigned short* __restrict__ Wf,  // [P*512, 512] bf16
    const float* __restrict__ bf,           // [P*512]
    const float* __restrict__ gates, const int* __restrict__ bidx,
    const int* __restrict__ eidx, float* __restrict__ out, int ebase) {
  __shared__ unsigned short ldsA[128 * 64];
  __shared__ unsigned short ldsB[128 * 64];
  int tid = threadIdx.x;
  int lane = tid & 63, w = tid >> 6;
  int wr0 = (w >> 1) * 64, wc0 = (w & 1) * 64;
  int tileM = blockIdx.x, tileN = blockIdx.y;
  const unsigned short* Ag = A + (size_t)tileM * 128 * KDIM;
  const unsigned short* Bg = Wf + (size_t)tileN * 128 * KDIM;
  f32x4 acc[4][4] = {};
  gemm_tile_k512(Ag, Bg, ldsA, ldsB, tid, acc);

  int j = (tileN * 128) >> 9;
  int obase = (tileN * 128) & 511;
  float bv[4];
  int ocol[4];
#pragma unroll
  for (int fj = 0; fj < 4; ++fj) {
    ocol[fj] = obase + wc0 + fj * 16 + (lane & 15);
    bv[fj] = bf[(j << 9) + ocol[fj]];
  }
#pragma unroll
  for (int fi = 0; fi < 4; ++fi) {
    int m0 = tileM * 128 + wr0 + fi * 16 + (lane >> 4) * 4;
    int n = m0 / L, li = m0 % L;
    int b = bidx[ebase + n];
    float g = gates[b * 4 + eidx[ebase + n]];
#pragma unroll
    for (int r = 0; r < 4; ++r) {
      if (li == L) { li = 0; ++n; b = bidx[ebase + n]; g = gates[b * 4 + eidx[ebase + n]]; }
      int t = li * P + j;
      float* orow = out + ((size_t)b * 336 + t) * 512;
      int bm4 = b & 3;
      bool first = (bm4 == 3) ? (EXPERT == 0) : (bm4 == EXPERT);
#pragma unroll
      for (int fj = 0; fj < 4; ++fj) {
        float v = g * (acc[fi][fj][r] + bv[fj]);
        if (first) orow[ocol[fj]] = v;
        else       orow[ocol[fj]] += v;
      }
      ++li;
    }
  }
}

extern "C" void kernel_launch(void* const* d_in, const int* in_sizes, int n_in,
                              void* d_out, int out_size, void* d_ws, size_t ws_size,
                              hipStream_t stream) {
  const float* xs[4]   = {(const float*)d_in[0], (const float*)d_in[3], (const float*)d_in[6], (const float*)d_in[9]};
  const float* Wfp[4]  = {(const float*)d_in[1], (const float*)d_in[4], (const float*)d_in[7], (const float*)d_in[10]};
  const float* bias[4] = {(const float*)d_in[2], (const float*)d_in[5], (const float*)d_in[8], (const float*)d_in[11]};
  const float* gates = (const float*)d_in[12];
  const float* Wp    = (const float*)d_in[13];
  const float* bp    = (const float*)d_in[14];
  const int* bidx    = (const int*)d_in[15];
  const int* eidx    = (const int*)d_in[16];

  static const int xs_elems[4] = {5505024, 2752512, 1835008, 917504};
  static const int W_elems[4]  = {1048576, 2097152, 3145728, 6291456};
  static const int Ps[4] = {4, 8, 12, 24};

  unsigned short* w = (unsigned short*)d_ws;
  size_t off = 0;
  unsigned short* xsb[4]; unsigned short* WtB[4]; unsigned short* Wfb[4];
  for (int i = 0; i < 4; i++) { xsb[i] = w + off; off += xs_elems[i]; }
  for (int i = 0; i < 4; i++) { WtB[i] = w + off; off += W_elems[i]; }
  for (int i = 0; i < 4; i++) { Wfb[i] = w + off; off += W_elems[i]; }
  unsigned short* Wpb = w + off; off += 262144;
  if (off & 1) off++;
  float* bfused = (float*)(w + off);  // 48*512 floats (24576 * 2 ushorts)

  // x and Wp -> bf16
  for (int i = 0; i < 4; i++) {
    int n8 = xs_elems[i] / 8;
    cvt_kernel<<<(n8 + 255) / 256, 256, 0, stream>>>(xs[i], xsb[i], n8);
  }
  cvt_kernel<<<(262144 / 8 + 255) / 256, 256, 0, stream>>>(Wp, Wpb, 262144 / 8);

  // W -> transposed per-j blocks (bf16)
  for (int i = 0; i < 4; i++) {
    dim3 grid(Ps[i] * 8, 8);
    transpose_cvt<<<grid, 256, 0, stream>>>(Wfp[i], WtB[i]);
  }

  // Wf = Wp @ W_j blocks  (bf16 out, fp32 accum)
  for (int i = 0; i < 4; i++) {
    dim3 grid(Ps[i] * 4, 4);
    fuse_gemm<<<grid, 256, 0, stream>>>(Wpb, WtB[i], Wfb[i]);
  }

  // fused bias per expert: bf = Wp @ b_j + bp
  static const int cumP[4] = {0, 4, 12, 24};
  for (int i = 0; i < 4; i++)
    bias_fuse<<<Ps[i], 256, 0, stream>>>(Wp, bias[i], bp, bfused + cumP[i] * 512);

  // fused expert GEMM + gated scatter-combine (no memset, no atomics)
  expert_fused<84, 4, 0><<<dim3(84, 16), 256, 0, stream>>>(xsb[0], Wfb[0], bfused + 0 * 512,    gates, bidx, eidx, (float*)d_out, 0);
  expert_fused<42, 8, 1><<<dim3(42, 32), 256, 0, stream>>>(xsb[1], Wfb[1], bfused + 4 * 512,    gates, bidx, eidx, (float*)d_out, 128);
  expert_fused<28, 12, 2><<<dim3(28, 48), 256, 0, stream>>>(xsb[2], Wfb[2], bfused + 12 * 512,  gates, bidx, eidx, (float*)d_out, 256);
  expert_fused<14, 24, 3><<<dim3(14, 96), 256, 0, stream>>>(xsb[3], Wfb[3], bfused + 24 * 512,  gates, bidx, eidx, (float*)d_out, 384);
}

// Round 3
// 337.836 us; speedup vs baseline: 2.2065x; 1.4055x over previous
//
#include <hip/hip_runtime.h>
#include <stdint.h>

typedef __bf16 bf16_t;
typedef bf16_t bf16x8 __attribute__((ext_vector_type(8)));
typedef float f32x4 __attribute__((ext_vector_type(4)));
typedef unsigned short u16x8 __attribute__((ext_vector_type(8)));

#define KDIM 512

__device__ __forceinline__ unsigned short f2bf(float f) {
  unsigned int u = __float_as_uint(f);
  u = (u + 0x7FFFu + ((u >> 16) & 1u)) >> 16;
  return (unsigned short)u;
}

// ================= merged fp32->bf16 conversion (5 segments, 8 elems/thread) =================
struct CvtArgs {
  const float *s0, *s1, *s2, *s3, *s4;
  unsigned short *d0, *d1, *d2, *d3, *d4;
};
// segment n8 sizes: 688128, 344064, 229376, 114688, 32768 ; cum: 688128,1032192,1261568,1376256,1409024
__device__ __forceinline__ void cvt8(const float* s, unsigned short* d, int i) {
  const float4* sp = (const float4*)s;
  float4 a = sp[2 * (size_t)i], b = sp[2 * (size_t)i + 1];
  u16x8 r;
  r[0] = f2bf(a.x); r[1] = f2bf(a.y); r[2] = f2bf(a.z); r[3] = f2bf(a.w);
  r[4] = f2bf(b.x); r[5] = f2bf(b.y); r[6] = f2bf(b.z); r[7] = f2bf(b.w);
  *(u16x8*)(d + (size_t)8 * i) = r;
}
__global__ void cvt_multi(CvtArgs a) {
  int i = blockIdx.x * blockDim.x + threadIdx.x;
  if (i < 688128)       cvt8(a.s0, a.d0, i);
  else if (i < 1032192) cvt8(a.s1, a.d1, i - 688128);
  else if (i < 1261568) cvt8(a.s2, a.d2, i - 1032192);
  else if (i < 1376256) cvt8(a.s3, a.d3, i - 1261568);
  else                  cvt8(a.s4, a.d4, i - 1376256);
}

// ================= merged transpose+cvt: W[p*512,512] fp32 -> WtB[p][512 d][512 e] bf16 =========
struct TpArgs {
  const float *w0, *w1, *w2, *w3;
  unsigned short *t0, *t1, *t2, *t3;
};
// per-expert blocks = 64*P: cum {256, 768, 1536, 3072}
__global__ __launch_bounds__(256) void transpose_all(TpArgs a) {
  __shared__ float tile[64][65];
  int bid = blockIdx.x;
  int e, base, P;
  if (bid < 256)       { e = 0; base = 0;    P = 4; }
  else if (bid < 768)  { e = 1; base = 256;  P = 8; }
  else if (bid < 1536) { e = 2; base = 768;  P = 12; }
  else                 { e = 3; base = 1536; P = 24; }
  const float* W = e == 0 ? a.w0 : e == 1 ? a.w1 : e == 2 ? a.w2 : a.w3;
  unsigned short* Wt = e == 0 ? a.t0 : e == 1 ? a.t1 : e == 2 ? a.t2 : a.t3;
  int r = bid - base;
  int qb = r % (P * 8), db = r / (P * 8);
  int q0 = qb * 64, d0 = db * 64;
  int t = threadIdx.x;
  int c = t & 63, r4 = t >> 6;
#pragma unroll
  for (int i = 0; i < 16; ++i) {
    int row = r4 + i * 4;
    tile[row][c] = W[(size_t)(q0 + row) * 512 + d0 + c];
  }
  __syncthreads();
  int j = q0 >> 9, e0 = q0 & 511;
  size_t obase = (size_t)j * 262144 + (size_t)d0 * 512 + e0;
#pragma unroll
  for (int i = 0; i < 16; ++i) {
    int dd = r4 + i * 4;
    Wt[obase + (size_t)dd * 512 + c] = f2bf(tile[c][dd]);
  }
}

// ================= merged fused bias: bf[jg*512+o] = Wp[o,:]@b_e[jl*512:]+bp[o] ================
struct BiasArgs { const float *b0, *b1, *b2, *b3; };
__global__ void bias_all(const float* __restrict__ Wp, BiasArgs a,
                         const float* __restrict__ bp, float* __restrict__ bf) {
  int jg = blockIdx.x;  // 0..47
  int e, base;
  if (jg < 4)       { e = 0; base = 0; }
  else if (jg < 12) { e = 1; base = 4; }
  else if (jg < 24) { e = 2; base = 12; }
  else              { e = 3; base = 24; }
  const float* b = e == 0 ? a.b0 : e == 1 ? a.b1 : e == 2 ? a.b2 : a.b3;
  int jl = jg - base;
  for (int o = threadIdx.x; o < 512; o += blockDim.x) {
    float s = bp[o];
    const float* wr = Wp + (size_t)o * 512;
    const float* br = b + (size_t)jl * 512;
    for (int ee = 0; ee < 512; ++ee) s += wr[ee] * br[ee];
    bf[(size_t)jg * 512 + o] = s;
  }
}

// ================= async global->LDS staging of a 128x64 bf16 tile (rule #21 swizzle) ==========
__device__ __forceinline__ void gload_lds16(const unsigned short* g, unsigned short* l) {
  __builtin_amdgcn_global_load_lds(
      (const __attribute__((address_space(1))) void*)g,
      (__attribute__((address_space(3))) void*)l, 16, 0, 0);
}

__device__ __forceinline__ void stage_tile(const unsigned short* __restrict__ gbase,
                                           unsigned short* lds, int tid) {
#pragma unroll
  for (int i = 0; i < 4; ++i) {
    int lin = i * 4096 + tid * 16;        // linear byte offset in LDS
    int row = lin >> 7;                   // 128 B per row
    int colb = lin & 127;
    int scolb = colb ^ ((row & 7) << 4);  // inverse-swizzled source byte col
    gload_lds16(gbase + (size_t)row * KDIM + (scolb >> 1), lds + (lin >> 1));
  }
}

// ================= double-buffered 128x128 bf16 MFMA tile, K=512 (2-phase, T3 minimum) =========
// LDS layout (ushort units): A0 @0, B0 @8192, A1 @16384, B1 @24576 (64 KiB total).
__device__ __forceinline__ void gemm_dbuf_k512(
    const unsigned short* __restrict__ Ag, const unsigned short* __restrict__ Bg,
    unsigned short* lds, int tid, f32x4 acc[4][4]) {
  int lane = tid & 63;
  int w = tid >> 6;
  int wr0 = (w >> 1) * 64, wc0 = (w & 1) * 64;
  stage_tile(Ag, lds, tid);
  stage_tile(Bg, lds + 8192, tid);
  __syncthreads();
#pragma unroll
  for (int kt = 0; kt < 8; ++kt) {
    unsigned short* curA = lds + ((kt & 1) ? 16384 : 0);
    unsigned short* curB = lds + ((kt & 1) ? 24576 : 8192);
    if (kt < 7) {  // issue next-tile STAGE before compute (overlaps with MFMA below)
      unsigned short* nxtA = lds + ((kt & 1) ? 0 : 16384);
      unsigned short* nxtB = lds + ((kt & 1) ? 8192 : 24576);
      stage_tile(Ag + (kt + 1) * 64, nxtA, tid);
      stage_tile(Bg + (kt + 1) * 64, nxtB, tid);
    }
#pragma unroll
    for (int kk = 0; kk < 2; ++kk) {
      bf16x8 av[4], bv[4];
      int cb = kk * 64 + (lane >> 4) * 16;
#pragma unroll
      for (int f = 0; f < 4; ++f) {
        int ra = wr0 + f * 16 + (lane & 15);
        av[f] = *(const bf16x8*)((const char*)curA + ra * 128 + (cb ^ ((ra & 7) << 4)));
        int rb = wc0 + f * 16 + (lane & 15);
        bv[f] = *(const bf16x8*)((const char*)curB + rb * 128 + (cb ^ ((rb & 7) << 4)));
      }
#pragma unroll
      for (int fi = 0; fi < 4; ++fi)
#pragma unroll
        for (int fj = 0; fj < 4; ++fj)
          acc[fi][fj] = __builtin_amdgcn_mfma_f32_16x16x32_bf16(av[fi], bv[fj], acc[fi][fj], 0, 0, 0);
    }
    __syncthreads();  // drains vmcnt (next-tile stage) + lgkm; one barrier per K-tile
  }
}

// ================= merged weight-fuse GEMM: Wf[(j,o),d] = sum_e Wp[o,e]*WtB[j][d][e] ===========
// per-expert tiles: tileM in [0,4P), tileN in [0,4); blocks = 16P: cum {64, 192, 384, 768}
struct FuseArgs {
  const unsigned short *wt0, *wt1, *wt2, *wt3;
  unsigned short *wf0, *wf1, *wf2, *wf3;
};
__global__ __launch_bounds__(256) void fuse_all(const unsigned short* __restrict__ Wpb, FuseArgs a) {
  __shared__ unsigned short lds[32768];
  int bid = blockIdx.x;
  int e, base, P;
  if (bid < 64)       { e = 0; base = 0;   P = 4; }
  else if (bid < 192) { e = 1; base = 64;  P = 8; }
  else if (bid < 384) { e = 2; base = 192; P = 12; }
  else                { e = 3; base = 384; P = 24; }
  const unsigned short* WtB = e == 0 ? a.wt0 : e == 1 ? a.wt1 : e == 2 ? a.wt2 : a.wt3;
  unsigned short* Wf = e == 0 ? a.wf0 : e == 1 ? a.wf1 : e == 2 ? a.wf2 : a.wf3;
  int r = bid - base;
  int tileM = r % (4 * P), tileN = r / (4 * P);
  int tid = threadIdx.x;
  int lane = tid & 63, w = tid >> 6;
  int wr0 = (w >> 1) * 64, wc0 = (w & 1) * 64;
  int j = (tileM * 128) >> 9;
  const unsigned short* Ag = Wpb + (size_t)((tileM * 128) & 511) * 512;
  const unsigned short* Bg = WtB + (size_t)j * 262144 + (size_t)(tileN * 128) * 512;
  f32x4 acc[4][4] = {};
  gemm_dbuf_k512(Ag, Bg, lds, tid, acc);
#pragma unroll
  for (int fi = 0; fi < 4; ++fi)
#pragma unroll
    for (int fj = 0; fj < 4; ++fj) {
      int col = tileN * 128 + wc0 + fj * 16 + (lane & 15);
#pragma unroll
      for (int r2 = 0; r2 < 4; ++r2) {
        int m = tileM * 128 + wr0 + fi * 16 + (lane >> 4) * 4 + r2;
        Wf[(size_t)m * 512 + col] = f2bf(acc[fi][fj][r2]);
      }
    }
}

// ================= fused expert GEMM + gate + scatter-combine (4 serialized launches) ==========
// First-writer per batch is static: b%4==3 -> expert 0, else expert b%4.  Plain RMW is
// race-free: one touch per element per kernel; the 4 expert kernels are stream-serialized.
// (Do NOT merge these launches: store/add ordering relies on stream serialization.)
template <int L, int P, int EXPERT>
__global__ __launch_bounds__(256) void expert_fused(
    const unsigned short* __restrict__ A,   // x bf16 [128*L, 512]
    const unsigned short* __restrict__ Wf,  // [P*512, 512] bf16
    const float* __restrict__ bf,           // [P*512]
    const float* __restrict__ gates, const int* __restrict__ bidx,
    const int* __restrict__ eidx, float* __restrict__ out, int ebase) {
  __shared__ unsigned short lds[32768];
  int tid = threadIdx.x;
  int lane = tid & 63, w = tid >> 6;
  int wr0 = (w >> 1) * 64, wc0 = (w & 1) * 64;
  int tileM = blockIdx.x, tileN = blockIdx.y;
  const unsigned short* Ag = A + (size_t)tileM * 128 * KDIM;
  const unsigned short* Bg = Wf + (size_t)tileN * 128 * KDIM;
  f32x4 acc[4][4] = {};
  gemm_dbuf_k512(Ag, Bg, lds, tid, acc);

  int j = (tileN * 128) >> 9;
  int obase = (tileN * 128) & 511;
  float bv[4];
  int ocol[4];
#pragma unroll
  for (int fj = 0; fj < 4; ++fj) {
    ocol[fj] = obase + wc0 + fj * 16 + (lane & 15);
    bv[fj] = bf[(j << 9) + ocol[fj]];
  }
#pragma unroll
  for (int fi = 0; fi < 4; ++fi) {
    int m0 = tileM * 128 + wr0 + fi * 16 + (lane >> 4) * 4;
    int n = m0 / L, li = m0 % L;
    int b = bidx[ebase + n];
    float g = gates[b * 4 + eidx[ebase + n]];
#pragma unroll
    for (int r = 0; r < 4; ++r) {
      if (li == L) { li = 0; ++n; b = bidx[ebase + n]; g = gates[b * 4 + eidx[ebase + n]]; }
      int t = li * P + j;
      float* orow = out + ((size_t)b * 336 + t) * 512;
      int bm4 = b & 3;
      bool first = (bm4 == 3) ? (EXPERT == 0) : (bm4 == EXPERT);
#pragma unroll
      for (int fj = 0; fj < 4; ++fj) {
        float v = g * (acc[fi][fj][r] + bv[fj]);
        if (first) orow[ocol[fj]] = v;
        else       orow[ocol[fj]] += v;
      }
      ++li;
    }
  }
}

extern "C" void kernel_launch(void* const* d_in, const int* in_sizes, int n_in,
                              void* d_out, int out_size, void* d_ws, size_t ws_size,
                              hipStream_t stream) {
  const float* xs[4]   = {(const float*)d_in[0], (const float*)d_in[3], (const float*)d_in[6], (const float*)d_in[9]};
  const float* Wfp[4]  = {(const float*)d_in[1], (const float*)d_in[4], (const float*)d_in[7], (const float*)d_in[10]};
  const float* bias[4] = {(const float*)d_in[2], (const float*)d_in[5], (const float*)d_in[8], (const float*)d_in[11]};
  const float* gates = (const float*)d_in[12];
  const float* Wp    = (const float*)d_in[13];
  const float* bp    = (const float*)d_in[14];
  const int* bidx    = (const int*)d_in[15];
  const int* eidx    = (const int*)d_in[16];

  static const int xs_elems[4] = {5505024, 2752512, 1835008, 917504};
  static const int W_elems[4]  = {1048576, 2097152, 3145728, 6291456};

  unsigned short* w = (unsigned short*)d_ws;
  size_t off = 0;
  unsigned short* xsb[4]; unsigned short* WtB[4]; unsigned short* Wfb[4];
  for (int i = 0; i < 4; i++) { xsb[i] = w + off; off += xs_elems[i]; }
  for (int i = 0; i < 4; i++) { WtB[i] = w + off; off += W_elems[i]; }
  for (int i = 0; i < 4; i++) { Wfb[i] = w + off; off += W_elems[i]; }
  unsigned short* Wpb = w + off; off += 262144;
  float* bfused = (float*)(w + off);  // 48*512 floats

  // --- prep: 4 launches total ---
  CvtArgs ca = {xs[0], xs[1], xs[2], xs[3], Wp, xsb[0], xsb[1], xsb[2], xsb[3], Wpb};
  cvt_multi<<<5504, 256, 0, stream>>>(ca);

  TpArgs ta = {Wfp[0], Wfp[1], Wfp[2], Wfp[3], WtB[0], WtB[1], WtB[2], WtB[3]};
  transpose_all<<<3072, 256, 0, stream>>>(ta);

  FuseArgs fa = {WtB[0], WtB[1], WtB[2], WtB[3], Wfb[0], Wfb[1], Wfb[2], Wfb[3]};
  fuse_all<<<768, 256, 0, stream>>>(Wpb, fa);

  BiasArgs ba = {bias[0], bias[1], bias[2], bias[3]};
  bias_all<<<48, 256, 0, stream>>>(Wp, ba, bp, bfused);

  // --- fused expert GEMM + gated scatter-combine (no memset, no atomics) ---
  expert_fused<84, 4, 0><<<dim3(84, 16), 256, 0, stream>>>(xsb[0], Wfb[0], bfused + 0 * 512,   gates, bidx, eidx, (float*)d_out, 0);
  expert_fused<42, 8, 1><<<dim3(42, 32), 256, 0, stream>>>(xsb[1], Wfb[1], bfused + 4 * 512,   gates, bidx, eidx, (float*)d_out, 128);
  expert_fused<28, 12, 2><<<dim3(28, 48), 256, 0, stream>>>(xsb[2], Wfb[2], bfused + 12 * 512, gates, bidx, eidx, (float*)d_out, 256);
  expert_fused<14, 24, 3><<<dim3(14, 96), 256, 0, stream>>>(xsb[3], Wfb[3], bfused + 24 * 512, gates, bidx, eidx, (float*)d_out, 384);
}